// Round 1
// baseline (240.425 us; speedup 1.0000x reference)
//
#include <hip/hip_runtime.h>
#include <hip/hip_bf16.h>

// Fused: fake_quant(x) -> conv1d(4->8,k=3,pad=1) w/ BN-folded quantized weights
//        -> fake_quant -> conv1d(8->2,k=3,pad=1) quantized weights -> fake_quant.
// One pass over x, never materializing y in global memory.

#define T 8  // output positions per thread

__device__ __forceinline__ float fq8(float v) {
    // trax symmetric fake-quant, bits=8: clip(floor(v*128+0.5), -128, 127)/128
    // v*128 is exact (power of two), so fma(v,128,0.5) == (v*128)+0.5 bit-exact.
    float t = floorf(fmaf(v, 128.0f, 0.5f));
    t = fmaxf(t, -128.0f);
    t = fminf(t, 127.0f);
    return t * 0.0078125f;  // * 1/128
}

__global__ __launch_bounds__(256) void fused_qconv_kernel(
    const float* __restrict__ x,
    const float* __restrict__ w1, const float* __restrict__ b1,
    const float* __restrict__ gamma, const float* __restrict__ beta,
    const float* __restrict__ bn_mean, const float* __restrict__ bn_var,
    const float* __restrict__ w2, const float* __restrict__ b2,
    float* __restrict__ out,
    int L, int chunksPerRow, int totalChunks)
{
    // ---- per-block quantized weight table in LDS (616 B) ----
    __shared__ float s_wq[96];   // [8][4][3] BN-folded, fake-quantized
    __shared__ float s_bq[8];
    __shared__ float s_w2q[48];  // [2][8][3]
    __shared__ float s_b2q[2];

    const int t = threadIdx.x;
    if (t < 96) {
        int c = t / 12;  // flat t == c*12 + i*3 + k, matches w1 layout
        float sf = gamma[c] * (1.0f / sqrtf(bn_var[c] + 1e-5f));
        s_wq[t] = fq8(w1[t] * sf);
    } else if (t < 104) {
        int c = t - 96;
        float sf = gamma[c] * (1.0f / sqrtf(bn_var[c] + 1e-5f));
        s_bq[c] = fq8((b1[c] - bn_mean[c]) * sf + beta[c]);
    } else if (t < 152) {
        s_w2q[t - 104] = fq8(w2[t - 104]);
    } else if (t < 154) {
        s_b2q[t - 152] = fq8(b2[t - 152]);
    }
    __syncthreads();

    const int chunk = blockIdx.x * blockDim.x + t;
    if (chunk >= totalChunks) return;
    const int n  = chunk / chunksPerRow;
    const int pc = chunk - n * chunksPerRow;
    const long pos0 = (long)pc * T;
    const bool le = (pos0 == 0);
    const bool re = (pos0 + T == L);

    // ---- load + quantize x window: positions pos0-2 .. pos0+T+1 (12 per channel) ----
    float xq[4][T + 4];
    const float* xb = x + ((size_t)n * 4) * (size_t)L + pos0;
#pragma unroll
    for (int i = 0; i < 4; ++i) {
        const float* xr = xb + (size_t)i * (size_t)L;
        float4 a = *(const float4*)(xr);       // pos0..pos0+3
        float4 b = *(const float4*)(xr + 4);   // pos0+4..pos0+7
        xq[i][2] = fq8(a.x); xq[i][3] = fq8(a.y); xq[i][4] = fq8(a.z); xq[i][5] = fq8(a.w);
        xq[i][6] = fq8(b.x); xq[i][7] = fq8(b.y); xq[i][8] = fq8(b.z); xq[i][9] = fq8(b.w);
        xq[i][0]      = le ? 0.0f : fq8(xr[-2]);
        xq[i][1]      = le ? 0.0f : fq8(xr[-1]);
        xq[i][T + 2]  = re ? 0.0f : fq8(xr[T]);
        xq[i][T + 3]  = re ? 0.0f : fq8(xr[T + 1]);
    }

    // ---- accumulators for conv2 output (2 out-ch x T positions) ----
    float acc[2][T];
#pragma unroll
    for (int j = 0; j < T; ++j) { acc[0][j] = s_b2q[0]; acc[1][j] = s_b2q[1]; }

    // channel-outer loop: only 19 weights live at a time
#pragma unroll
    for (int c = 0; c < 8; ++c) {
        float wc[12];
#pragma unroll
        for (int q = 0; q < 12; ++q) wc[q] = s_wq[c * 12 + q];
        const float bc  = s_bq[c];
        const float w20 = s_w2q[c * 3 + 0];
        const float w21 = s_w2q[c * 3 + 1];
        const float w22 = s_w2q[c * 3 + 2];
        const float w23 = s_w2q[24 + c * 3 + 0];
        const float w24 = s_w2q[24 + c * 3 + 1];
        const float w25 = s_w2q[24 + c * 3 + 2];

        // y positions l' = pos0-1+p for p in [0, T+2)
#pragma unroll
        for (int p = 0; p < T + 2; ++p) {
            float v = bc;
#pragma unroll
            for (int i = 0; i < 4; ++i) {
                v = fmaf(xq[i][p + 0], wc[i * 3 + 0], v);
                v = fmaf(xq[i][p + 1], wc[i * 3 + 1], v);
                v = fmaf(xq[i][p + 2], wc[i * 3 + 2], v);
            }
            float yv = fq8(v);
            // conv2 zero-padding: y[-1] and y[L] are padding zeros, not conv output
            if (p == 0     && le) yv = 0.0f;
            if (p == T + 1 && re) yv = 0.0f;
            // scatter into z: y[l'] -> z[l'+1-k] with weight w2[k]
            if (p < T) {
                acc[0][p] = fmaf(yv, w20, acc[0][p]);
                acc[1][p] = fmaf(yv, w23, acc[1][p]);
            }
            if (p >= 1 && p - 1 < T) {
                acc[0][p - 1] = fmaf(yv, w21, acc[0][p - 1]);
                acc[1][p - 1] = fmaf(yv, w24, acc[1][p - 1]);
            }
            if (p >= 2) {
                acc[0][p - 2] = fmaf(yv, w22, acc[0][p - 2]);
                acc[1][p - 2] = fmaf(yv, w25, acc[1][p - 2]);
            }
        }
    }

    // ---- final quantize + vectorized store ----
    float* ob = out + ((size_t)n * 2) * (size_t)L + pos0;
#pragma unroll
    for (int o = 0; o < 2; ++o) {
        float4 r0, r1;
        r0.x = fq8(acc[o][0]); r0.y = fq8(acc[o][1]); r0.z = fq8(acc[o][2]); r0.w = fq8(acc[o][3]);
        r1.x = fq8(acc[o][4]); r1.y = fq8(acc[o][5]); r1.z = fq8(acc[o][6]); r1.w = fq8(acc[o][7]);
        *(float4*)(ob + (size_t)o * (size_t)L)     = r0;
        *(float4*)(ob + (size_t)o * (size_t)L + 4) = r1;
    }
}

extern "C" void kernel_launch(void* const* d_in, const int* in_sizes, int n_in,
                              void* d_out, int out_size, void* d_ws, size_t ws_size,
                              hipStream_t stream) {
    const float* x       = (const float*)d_in[0];
    const float* w1      = (const float*)d_in[1];
    const float* b1      = (const float*)d_in[2];
    const float* gamma   = (const float*)d_in[3];
    const float* beta    = (const float*)d_in[4];
    const float* bn_mean = (const float*)d_in[5];
    const float* bn_var  = (const float*)d_in[6];
    const float* w2      = (const float*)d_in[7];
    const float* b2      = (const float*)d_in[8];
    float* out = (float*)d_out;

    const int B = 16;
    const int L = in_sizes[0] / (B * 4);
    const int chunksPerRow = L / T;            // L=524288 divisible by 8
    const int totalChunks  = B * chunksPerRow; // 1,048,576
    const int block = 256;
    const int grid = (totalChunks + block - 1) / block;

    fused_qconv_kernel<<<grid, block, 0, stream>>>(
        x, w1, b1, gamma, beta, bn_mean, bn_var, w2, b2, out,
        L, chunksPerRow, totalChunks);
}